// Round 1
// baseline (2212.294 us; speedup 1.0000x reference)
//
#include <hip/hip_runtime.h>

#define VOCAB  50257
#define VPAD   50304          // 64*786 padded vocab
#define SLICE  786            // vocab per slice (64 slices)
#define SDEC   63             // decode steps (S_TGT-1)
#define NBLK   256            // fused grid: 256 blocks (=#CUs, resident by construction)
#define NTHR   512            // 8 waves/block

struct Params {
  const int   *xsrc, *xtgt;
  const float *eemb, *eWih0, *eWhh0, *ebih0, *ebhh0, *eWih1, *eWhh1, *ebih1, *ebhh1;
  const float *demb, *dWih0, *dWhh0, *dbih0, *dbhh0, *dWih1, *dWhh1, *dbih1, *dbhh1;
  const float *fcW, *fcb;
  float *out;
  unsigned long long *win;   // [SDEC*32] packed argmax winners
  float *Sh0, *Sc0, *Sh1, *Sc1;  // [32*32] encoder-final -> decoder-init states
  unsigned *bar;             // grid barrier counter (zeroed by init_kernel each replay)
  float4 *fcp;               // [8*VPAD] transposed fc_W
  int use_pack;
};

__device__ __forceinline__ float sigm(float x) { return 1.f / (1.f + expf(-x)); }
__device__ __forceinline__ float dot4(float4 a, float4 b) {
  return a.x * b.x + a.y * b.y + a.z * b.z + a.w * b.w;
}

// ---------------- init: barrier/winner reset + fc_W transpose pack ----------------
__global__ __launch_bounds__(256) void init_kernel(Params p)
{
  const int tid = threadIdx.x, blk = blockIdx.x;
  if (blk == 0) {
    if (tid == 0) *p.bar = 0u;                       // MUST reset every graph replay
    for (int i = tid; i < SDEC * 32; i += 256) p.win[i] = 0ull;
  }
  if (p.use_pack) {
    const int gid = blk * 256 + tid, stride = 64 * 256;
    for (int v = gid; v < VOCAB; v += stride) {
      const float4* s = (const float4*)(p.fcW + (size_t)v * 32);
#pragma unroll
      for (int c = 0; c < 8; ++c) p.fcp[(size_t)c * VPAD + v] = s[c];
    }
  }
}

// grid barrier: monotone counter, one atomic per block. All 256 blocks are resident
// (1 block/CU by LDS+VGPR under __launch_bounds__(512,2)), so spinning is safe.
__device__ __forceinline__ void gsync(unsigned* bar, unsigned target)
{
  __syncthreads();
  if (threadIdx.x == 0) {
    __hip_atomic_fetch_add(bar, 1u, __ATOMIC_ACQ_REL, __HIP_MEMORY_SCOPE_AGENT);
    while (__hip_atomic_load(bar, __ATOMIC_RELAXED, __HIP_MEMORY_SCOPE_AGENT) < target)
      __builtin_amdgcn_s_sleep(1);
    (void)__hip_atomic_load(bar, __ATOMIC_ACQUIRE, __HIP_MEMORY_SCOPE_AGENT);
  }
  __syncthreads();
}

// ---------------- fused encoder + full greedy decode loop ----------------
// block b: vocab slice = b & 63, row-group rg = b >> 6 -> rows rg*8 .. rg*8+7.
// Same-slice blocks (b = slice + 64k) share b%8 -> same XCD L2 for fc weights.
__global__ __launch_bounds__(NTHR, 2) void fused_kernel(Params p)
{
  const int tid = threadIdx.x, blk = blockIdx.x;
  const int slice = blk & 63, rg = blk >> 6;
  const int R = rg * 8;
  const int v0 = slice * SLICE, v1 = min(VOCAB, v0 + SLICE);

  __shared__ __align__(16) float4 cw4[4096];               // 64KB: decoder weights, transposed
  __shared__ float sB[2][128];                             // combined per-layer biases
  __shared__ __align__(16) float sH0[8][32], sC0[8][32], sH1[8][32], sC1[8][32], sX[8][32];
  __shared__ __align__(16) float sG[8][128];
  __shared__ int sTok[8];
  __shared__ unsigned long long redw[8][4];
  __shared__ __align__(16) float eH0[32], eC0[32], eH1[32], eC1[32];  // encoder scratch
  __shared__ float eG[128];

  // decoder cell weights -> LDS: cw4[mat*1024 + jo*128 + g] = W_mat[g][4jo..4jo+3]
  // (read later with lane==g consecutive -> conflict-free ds_read_b128)
  for (int i = tid; i < 4096; i += NTHR) {
    const int mat = i >> 10, rem = i & 1023, jo = rem >> 7, g = rem & 127;
    const float* W = (mat == 0) ? p.dWih0 : (mat == 1) ? p.dWhh0
                   : (mat == 2) ? p.dWih1 : p.dWhh1;
    const float* s = W + g * 32 + jo * 4;
    cw4[i] = make_float4(s[0], s[1], s[2], s[3]);
  }
  if (tid < 128) {
    sB[0][tid] = p.dbih0[tid] + p.dbhh0[tid];
    sB[1][tid] = p.dbih1[tid] + p.dbhh1[tid];
  }

  // ---- phase A: blocks 0..31 run the encoder for batch row `blk` ----
  if (blk < 32) {
    float4 wi0[8], wh0[8], wi1[8], wh1[8];
    float bs0 = 0.f, bs1 = 0.f;
    if (tid < 128) {
      const float4* a0 = (const float4*)(p.eWih0 + tid * 32);
      const float4* b0 = (const float4*)(p.eWhh0 + tid * 32);
      const float4* a1 = (const float4*)(p.eWih1 + tid * 32);
      const float4* b1 = (const float4*)(p.eWhh1 + tid * 32);
#pragma unroll
      for (int c = 0; c < 8; ++c) { wi0[c] = a0[c]; wh0[c] = b0[c]; wi1[c] = a1[c]; wh1[c] = b1[c]; }
      bs0 = p.ebih0[tid] + p.ebhh0[tid];
      bs1 = p.ebih1[tid] + p.ebhh1[tid];
    }
    if (tid < 32) { eH0[tid] = 0.f; eC0[tid] = 0.f; eH1[tid] = 0.f; eC1[tid] = 0.f; }
    __syncthreads();
    for (int t = 0; t < 64; ++t) {
      const int tok = p.xsrc[t * 32 + blk];
      if (tid < 128) {
        const float4* xe = (const float4*)(p.eemb + (size_t)tok * 32);
        const float4* h4 = (const float4*)eH0;
        float a = bs0;
#pragma unroll
        for (int c = 0; c < 8; ++c) a += dot4(wi0[c], xe[c]) + dot4(wh0[c], h4[c]);
        eG[tid] = a;
      }
      __syncthreads();
      if (tid < 32) {
        float gi = sigm(eG[tid]), gf = sigm(eG[32 + tid]);
        float gg = tanhf(eG[64 + tid]), go = sigm(eG[96 + tid]);
        float c = gf * eC0[tid] + gi * gg;
        eC0[tid] = c; eH0[tid] = go * tanhf(c);
      }
      __syncthreads();
      if (tid < 128) {
        const float4* x4 = (const float4*)eH0;
        const float4* h4 = (const float4*)eH1;
        float a = bs1;
#pragma unroll
        for (int c = 0; c < 8; ++c) a += dot4(wi1[c], x4[c]) + dot4(wh1[c], h4[c]);
        eG[tid] = a;
      }
      __syncthreads();
      if (tid < 32) {
        float gi = sigm(eG[tid]), gf = sigm(eG[32 + tid]);
        float gg = tanhf(eG[64 + tid]), go = sigm(eG[96 + tid]);
        float c = gf * eC1[tid] + gi * gg;
        eC1[tid] = c; eH1[tid] = go * tanhf(c);
      }
      __syncthreads();
    }
    if (tid < 32) {   // agent-scope stores: visible across XCDs after the barrier
      __hip_atomic_store(&p.Sh0[blk * 32 + tid], eH0[tid], __ATOMIC_RELAXED, __HIP_MEMORY_SCOPE_AGENT);
      __hip_atomic_store(&p.Sc0[blk * 32 + tid], eC0[tid], __ATOMIC_RELAXED, __HIP_MEMORY_SCOPE_AGENT);
      __hip_atomic_store(&p.Sh1[blk * 32 + tid], eH1[tid], __ATOMIC_RELAXED, __HIP_MEMORY_SCOPE_AGENT);
      __hip_atomic_store(&p.Sc1[blk * 32 + tid], eC1[tid], __ATOMIC_RELAXED, __HIP_MEMORY_SCOPE_AGENT);
    }
  }

  gsync(p.bar, NBLK);         // encoder finals + LDS staging complete everywhere

  // each block pulls its 8 rows of decoder-initial state into LDS (kept local after)
  if (tid < 256) {
    const int r = tid >> 5, j = tid & 31, gi = (R + r) * 32 + j;
    sH0[r][j] = __hip_atomic_load(&p.Sh0[gi], __ATOMIC_RELAXED, __HIP_MEMORY_SCOPE_AGENT);
    sC0[r][j] = __hip_atomic_load(&p.Sc0[gi], __ATOMIC_RELAXED, __HIP_MEMORY_SCOPE_AGENT);
    sH1[r][j] = __hip_atomic_load(&p.Sh1[gi], __ATOMIC_RELAXED, __HIP_MEMORY_SCOPE_AGENT);
    sC1[r][j] = __hip_atomic_load(&p.Sc1[gi], __ATOMIC_RELAXED, __HIP_MEMORY_SCOPE_AGENT);
  }

  unsigned gen = 1;
  for (int t = 0; t < SDEC; ++t) {
    // ---- token + embedding for this block's 8 rows ----
    if (tid < 8) {
      int tok;
      if (t == 0) tok = p.xtgt[R + tid];
      else {
        unsigned long long w = __hip_atomic_load(&p.win[(t - 1) * 32 + R + tid],
                                                 __ATOMIC_RELAXED, __HIP_MEMORY_SCOPE_AGENT);
        tok = (int)(~(unsigned)w);
      }
      sTok[tid] = tok;
    }
    __syncthreads();
    if (tid < 64) {
      const int r = tid >> 3, c = tid & 7;
      ((float4*)sX[r])[c] = ((const float4*)(p.demb + (size_t)sTok[r] * 32))[c];
    }
    __syncthreads();

    // ---- LSTM layer 0 (rows local; thread = gate g for 2 rows) ----
    {
      const int g = tid & 127, rp = tid >> 7;
      float4 wi[8], wh[8];
#pragma unroll
      for (int jo = 0; jo < 8; ++jo) { wi[jo] = cw4[jo * 128 + g]; wh[jo] = cw4[1024 + jo * 128 + g]; }
      const float bb = sB[0][g];
#pragma unroll
      for (int rr = 0; rr < 2; ++rr) {
        const int r = rp * 2 + rr;
        const float4* x4 = (const float4*)sX[r];
        const float4* h4 = (const float4*)sH0[r];
        float a = bb;
#pragma unroll
        for (int jo = 0; jo < 8; ++jo) a += dot4(wi[jo], x4[jo]) + dot4(wh[jo], h4[jo]);
        sG[r][g] = a;
      }
    }
    __syncthreads();
    if (tid < 256) {
      const int r = tid >> 5, j = tid & 31;
      const float gi = sigm(sG[r][j]), gf = sigm(sG[r][32 + j]);
      const float gg = tanhf(sG[r][64 + j]), go = sigm(sG[r][96 + j]);
      const float c = gf * sC0[r][j] + gi * gg;
      sC0[r][j] = c; sH0[r][j] = go * tanhf(c);
    }
    __syncthreads();

    // ---- LSTM layer 1 (input = new h0) ----
    {
      const int g = tid & 127, rp = tid >> 7;
      float4 wi[8], wh[8];
#pragma unroll
      for (int jo = 0; jo < 8; ++jo) { wi[jo] = cw4[2048 + jo * 128 + g]; wh[jo] = cw4[3072 + jo * 128 + g]; }
      const float bb = sB[1][g];
#pragma unroll
      for (int rr = 0; rr < 2; ++rr) {
        const int r = rp * 2 + rr;
        const float4* x4 = (const float4*)sH0[r];
        const float4* h4 = (const float4*)sH1[r];
        float a = bb;
#pragma unroll
        for (int jo = 0; jo < 8; ++jo) a += dot4(wi[jo], x4[jo]) + dot4(wh[jo], h4[jo]);
        sG[r][g] = a;
      }
    }
    __syncthreads();
    if (tid < 256) {
      const int r = tid >> 5, j = tid & 31;
      const float gi = sigm(sG[r][j]), gf = sigm(sG[r][32 + j]);
      const float gg = tanhf(sG[r][64 + j]), go = sigm(sG[r][96 + j]);
      const float c = gf * sC1[r][j] + gi * gg;
      sC1[r][j] = c; sH1[r][j] = go * tanhf(c);
    }
    __syncthreads();

    // ---- logits + argmax: waves 0-3 -> rows R..R+3, waves 4-7 -> rows R+4..R+7 ----
    {
      const int half = tid >> 8, lane256 = tid & 255;
      float4 hr[4][8];
#pragma unroll
      for (int k = 0; k < 4; ++k) {
        const float4* h4 = (const float4*)sH1[half * 4 + k];
#pragma unroll
        for (int c = 0; c < 8; ++c) hr[k][c] = h4[c];
      }
      unsigned long long best[4] = {0ull, 0ull, 0ull, 0ull};
      const size_t ob = ((size_t)t * 32 + R + half * 4) * VOCAB;
      for (int v = v0 + lane256; v < v1; v += 256) {
        float4 w0, w1, w2, w3, w4, w5, w6, w7;
        if (p.use_pack) {
          w0 = p.fcp[v];              w1 = p.fcp[VPAD + v];
          w2 = p.fcp[2 * VPAD + v];   w3 = p.fcp[3 * VPAD + v];
          w4 = p.fcp[4 * VPAD + v];   w5 = p.fcp[5 * VPAD + v];
          w6 = p.fcp[6 * VPAD + v];   w7 = p.fcp[7 * VPAD + v];
        } else {
          const float4* wp = (const float4*)(p.fcW + (size_t)v * 32);
          w0 = wp[0]; w1 = wp[1]; w2 = wp[2]; w3 = wp[3];
          w4 = wp[4]; w5 = wp[5]; w6 = wp[6]; w7 = wp[7];
        }
        const float bb = p.fcb[v];
#pragma unroll
        for (int k = 0; k < 4; ++k) {
          float a = bb
            + dot4(hr[k][0], w0) + dot4(hr[k][1], w1) + dot4(hr[k][2], w2) + dot4(hr[k][3], w3)
            + dot4(hr[k][4], w4) + dot4(hr[k][5], w5) + dot4(hr[k][6], w6) + dot4(hr[k][7], w7);
          p.out[ob + (size_t)k * VOCAB + v] = a;
          unsigned ui = __float_as_uint(a);
          ui = (ui & 0x80000000u) ? ~ui : (ui | 0x80000000u);   // monotone float->uint
          const unsigned long long pk = ((unsigned long long)ui << 32) | (unsigned)(~(unsigned)v);
          if (pk > best[k]) best[k] = pk;   // ties -> smallest v (matches jnp.argmax)
        }
      }
#pragma unroll
      for (int off = 32; off > 0; off >>= 1)
#pragma unroll
        for (int k = 0; k < 4; ++k) {
          const unsigned long long o = __shfl_down(best[k], (unsigned)off, 64);
          if (o > best[k]) best[k] = o;
        }
      if ((tid & 63) == 0) {
        const int w = tid >> 6;
#pragma unroll
        for (int k = 0; k < 4; ++k) redw[w][k] = best[k];
      }
    }
    __syncthreads();
    if (tid < 8) {   // row R+tid: waves (tid>>2)*4 .. +3 hold its candidates
      const int wb = (tid >> 2) * 4, k = tid & 3;
      unsigned long long m = redw[wb][k];
      if (redw[wb + 1][k] > m) m = redw[wb + 1][k];
      if (redw[wb + 2][k] > m) m = redw[wb + 2][k];
      if (redw[wb + 3][k] > m) m = redw[wb + 3][k];
      __hip_atomic_fetch_max(&p.win[t * 32 + R + tid], m,
                             __ATOMIC_RELAXED, __HIP_MEMORY_SCOPE_AGENT);
    }

    ++gen;
    if (t != SDEC - 1) gsync(p.bar, NBLK * gen);   // winners final -> next step may read
  }
}

extern "C" void kernel_launch(void* const* d_in, const int* in_sizes, int n_in,
                              void* d_out, int out_size, void* d_ws, size_t ws_size,
                              hipStream_t stream) {
  Params p;
  p.xsrc  = (const int*)d_in[0];
  p.xtgt  = (const int*)d_in[1];
  p.eemb  = (const float*)d_in[2];
  p.eWih0 = (const float*)d_in[3];
  p.eWhh0 = (const float*)d_in[4];
  p.ebih0 = (const float*)d_in[5];
  p.ebhh0 = (const float*)d_in[6];
  p.eWih1 = (const float*)d_in[7];
  p.eWhh1 = (const float*)d_in[8];
  p.ebih1 = (const float*)d_in[9];
  p.ebhh1 = (const float*)d_in[10];
  p.demb  = (const float*)d_in[11];
  p.dWih0 = (const float*)d_in[12];
  p.dWhh0 = (const float*)d_in[13];
  p.dbih0 = (const float*)d_in[14];
  p.dbhh0 = (const float*)d_in[15];
  p.dWih1 = (const float*)d_in[16];
  p.dWhh1 = (const float*)d_in[17];
  p.dbih1 = (const float*)d_in[18];
  p.dbhh1 = (const float*)d_in[19];
  p.fcW   = (const float*)d_in[20];
  p.fcb   = (const float*)d_in[21];
  p.out   = (float*)d_out;

  char* ws = (char*)d_ws;
  p.win = (unsigned long long*)(ws);           // 16384 B (need 16128)
  p.Sh0 = (float*)(ws + 16384);                // 4 KB each
  p.Sc0 = (float*)(ws + 20480);
  p.Sh1 = (float*)(ws + 24576);
  p.Sc1 = (float*)(ws + 28672);
  p.bar = (unsigned*)(ws + 32768);             // barrier counter
  p.fcp = (float4*)(ws + 98304);               // 8*VPAD*16 = 6438912 B
  const size_t need = 98304 + (size_t)8 * VPAD * 16;
  p.use_pack = (ws_size >= need) ? 1 : 0;      // fallback: row-major direct reads

  init_kernel<<<dim3(64), dim3(256), 0, stream>>>(p);
  fused_kernel<<<dim3(NBLK), dim3(NTHR), 0, stream>>>(p);
}

// Round 2
// 2134.138 us; speedup vs baseline: 1.0366x; 1.0366x over previous
//
#include <hip/hip_runtime.h>

#define VOCAB  50257
#define VPAD   50304          // 64*786 padded vocab
#define SLICE  786            // vocab per slice (64 slices)
#define SDEC   63             // decode steps (S_TGT-1)
#define NBLK   256            // 1 block/CU, all resident by resource arithmetic
#define NTHR   512            // 8 waves/block

struct Params {
  const int   *xsrc, *xtgt;
  const float *eemb, *eWih0, *eWhh0, *ebih0, *ebhh0, *eWih1, *eWhh1, *ebih1, *ebhh1;
  const float *demb, *dWih0, *dWhh0, *dbih0, *dbhh0, *dWih1, *dWhh1, *dbih1, *dbhh1;
  const float *fcW, *fcb;
  float *out;
  unsigned *sflag;              // [32] encoder-row done flags
  unsigned *dflag;              // [8][64] per-(rg,slice) monotone step counters
  unsigned long long *cand;     // [2][8][8][64] per-slice argmax candidates
  float *Sh0, *Sc0, *Sh1, *Sc1; // [32*32] encoder-final states
  float4 *fcp;                  // [8*VPAD] transposed fc_W
  int use_pack;
};

__device__ __forceinline__ float sigm(float x) { return 1.f / (1.f + expf(-x)); }
__device__ __forceinline__ float dot4(float4 a, float4 b) {
  return a.x * b.x + a.y * b.y + a.z * b.z + a.w * b.w;
}

// ---------------- init: flag reset + fc_W transpose pack ----------------
__global__ __launch_bounds__(256) void init_kernel(Params p)
{
  const int tid = threadIdx.x, blk = blockIdx.x;
  if (blk == 0) {
    if (tid < 32) p.sflag[tid] = 0u;                 // MUST reset every graph replay
    for (int i = tid; i < 8 * 64; i += 256) p.dflag[i] = 0u;
  }
  if (p.use_pack) {
    const int gid = blk * 256 + tid, stride = 64 * 256;
    for (int v = gid; v < VOCAB; v += stride) {
      const float4* s = (const float4*)(p.fcW + (size_t)v * 32);
#pragma unroll
      for (int c = 0; c < 8; ++c) p.fcp[(size_t)c * VPAD + v] = s[c];
    }
  }
}

// ---------------- fused encoder + full greedy decode, flag-synced ----------------
// block b: vocab slice = b & 63, row-group rg = b >> 6 -> rows rg*8 .. rg*8+7.
// blk%8 = slice%8 -> all 8 rg-duplicates of a slice share one XCD's L2 (~830KB/XCD).
__global__ __launch_bounds__(NTHR, 1) void fused_kernel(Params p)
{
  const int tid = threadIdx.x, blk = blockIdx.x;
  const int slice = blk & 63, rg = blk >> 6;
  const int R = rg * 8;
  const int v0 = slice * SLICE, v1 = min(VOCAB, v0 + SLICE);

  __shared__ __align__(16) float4 cw4[4096];               // 64KB decoder cell weights
  __shared__ float sB[2][128];
  __shared__ __align__(16) float sH0[8][32], sC0[8][32], sH1[8][32], sC1[8][32], sX[8][32];
  __shared__ __align__(16) float sG[8][128];
  __shared__ int sTok[8];
  __shared__ unsigned long long redw[8][4];
  __shared__ __align__(16) float eH0[32], eC0[32], eH1[32], eC1[32];
  __shared__ float eG[128];

  // decoder cell weights -> LDS (transposed, conflict-free b128 reads later)
  for (int i = tid; i < 4096; i += NTHR) {
    const int mat = i >> 10, rem = i & 1023, jo = rem >> 7, g = rem & 127;
    const float* W = (mat == 0) ? p.dWih0 : (mat == 1) ? p.dWhh0
                   : (mat == 2) ? p.dWih1 : p.dWhh1;
    const float* s = W + g * 32 + jo * 4;
    cw4[i] = make_float4(s[0], s[1], s[2], s[3]);
  }
  if (tid < 128) {
    sB[0][tid] = p.dbih0[tid] + p.dbhh0[tid];
    sB[1][tid] = p.dbih1[tid] + p.dbhh1[tid];
  }

  // ---- phase A: blocks 0..31 run the encoder for batch row `blk` ----
  if (blk < 32) {
    float4 wi0[8], wh0[8], wi1[8], wh1[8];
    float bs0 = 0.f, bs1 = 0.f;
    if (tid < 128) {
      const float4* a0 = (const float4*)(p.eWih0 + tid * 32);
      const float4* b0 = (const float4*)(p.eWhh0 + tid * 32);
      const float4* a1 = (const float4*)(p.eWih1 + tid * 32);
      const float4* b1 = (const float4*)(p.eWhh1 + tid * 32);
#pragma unroll
      for (int c = 0; c < 8; ++c) { wi0[c] = a0[c]; wh0[c] = b0[c]; wi1[c] = a1[c]; wh1[c] = b1[c]; }
      bs0 = p.ebih0[tid] + p.ebhh0[tid];
      bs1 = p.ebih1[tid] + p.ebhh1[tid];
    }
    if (tid < 32) { eH0[tid] = 0.f; eC0[tid] = 0.f; eH1[tid] = 0.f; eC1[tid] = 0.f; }
    __syncthreads();
    for (int t = 0; t < 64; ++t) {
      const int tok = p.xsrc[t * 32 + blk];
      if (tid < 128) {
        const float4* xe = (const float4*)(p.eemb + (size_t)tok * 32);
        const float4* h4 = (const float4*)eH0;
        float a = bs0;
#pragma unroll
        for (int c = 0; c < 8; ++c) a += dot4(wi0[c], xe[c]) + dot4(wh0[c], h4[c]);
        eG[tid] = a;
      }
      __syncthreads();
      if (tid < 32) {
        float gi = sigm(eG[tid]), gf = sigm(eG[32 + tid]);
        float gg = tanhf(eG[64 + tid]), go = sigm(eG[96 + tid]);
        float c = gf * eC0[tid] + gi * gg;
        eC0[tid] = c; eH0[tid] = go * tanhf(c);
      }
      __syncthreads();
      if (tid < 128) {
        const float4* x4 = (const float4*)eH0;
        const float4* h4 = (const float4*)eH1;
        float a = bs1;
#pragma unroll
        for (int c = 0; c < 8; ++c) a += dot4(wi1[c], x4[c]) + dot4(wh1[c], h4[c]);
        eG[tid] = a;
      }
      __syncthreads();
      if (tid < 32) {
        float gi = sigm(eG[tid]), gf = sigm(eG[32 + tid]);
        float gg = tanhf(eG[64 + tid]), go = sigm(eG[96 + tid]);
        float c = gf * eC1[tid] + gi * gg;
        eC1[tid] = c; eH1[tid] = go * tanhf(c);
      }
      __syncthreads();
    }
    if (tid < 32) {   // agent-scope stores, then release-flag from lane 0 (same wave)
      __hip_atomic_store(&p.Sh0[blk * 32 + tid], eH0[tid], __ATOMIC_RELAXED, __HIP_MEMORY_SCOPE_AGENT);
      __hip_atomic_store(&p.Sc0[blk * 32 + tid], eC0[tid], __ATOMIC_RELAXED, __HIP_MEMORY_SCOPE_AGENT);
      __hip_atomic_store(&p.Sh1[blk * 32 + tid], eH1[tid], __ATOMIC_RELAXED, __HIP_MEMORY_SCOPE_AGENT);
      __hip_atomic_store(&p.Sc1[blk * 32 + tid], eC1[tid], __ATOMIC_RELAXED, __HIP_MEMORY_SCOPE_AGENT);
    }
    if (tid == 0)   // RELEASE drains the state stores (vmcnt) before flag lands
      __hip_atomic_store(&p.sflag[blk], 1u, __ATOMIC_RELEASE, __HIP_MEMORY_SCOPE_AGENT);
  }

  // ---- wait only for THIS block's 8 rows of encoder state (no global barrier) ----
  if (tid < 8) {
    while (__hip_atomic_load(&p.sflag[R + tid], __ATOMIC_RELAXED, __HIP_MEMORY_SCOPE_AGENT) == 0u)
      __builtin_amdgcn_s_sleep(1);
    (void)__hip_atomic_load(&p.sflag[R + tid], __ATOMIC_ACQUIRE, __HIP_MEMORY_SCOPE_AGENT);
  }
  __syncthreads();
  if (tid < 256) {
    const int r = tid >> 5, j = tid & 31, gi = (R + r) * 32 + j;
    sH0[r][j] = __hip_atomic_load(&p.Sh0[gi], __ATOMIC_RELAXED, __HIP_MEMORY_SCOPE_AGENT);
    sC0[r][j] = __hip_atomic_load(&p.Sc0[gi], __ATOMIC_RELAXED, __HIP_MEMORY_SCOPE_AGENT);
    sH1[r][j] = __hip_atomic_load(&p.Sh1[gi], __ATOMIC_RELAXED, __HIP_MEMORY_SCOPE_AGENT);
    sC1[r][j] = __hip_atomic_load(&p.Sc1[gi], __ATOMIC_RELAXED, __HIP_MEMORY_SCOPE_AGENT);
  }
  __syncthreads();

  for (int t = 0; t < SDEC; ++t) {
    // ---- tokens: xtgt at t=0, else reduce the 64 slice-candidates of each row ----
    if (t == 0) {
      if (tid < 8) sTok[tid] = p.xtgt[R + tid];
      __syncthreads();
    } else {
      if (tid < 64) {   // one flag per polling thread; read-only, no RMW contention
        while (__hip_atomic_load(&p.dflag[rg * 64 + tid], __ATOMIC_RELAXED, __HIP_MEMORY_SCOPE_AGENT) < (unsigned)t)
          __builtin_amdgcn_s_sleep(1);
        (void)__hip_atomic_load(&p.dflag[rg * 64 + tid], __ATOMIC_ACQUIRE, __HIP_MEMORY_SCOPE_AGENT);
      }
      __syncthreads();
      const int w = tid >> 6, ln = tid & 63;     // wave w reduces row R+w
      unsigned long long b = __hip_atomic_load(
          &p.cand[(((size_t)((t - 1) & 1) * 8 + rg) * 8 + w) * 64 + ln],
          __ATOMIC_RELAXED, __HIP_MEMORY_SCOPE_AGENT);
#pragma unroll
      for (int off = 32; off > 0; off >>= 1) {
        const unsigned long long o = __shfl_down(b, (unsigned)off, 64);
        if (o > b) b = o;
      }
      if (ln == 0) sTok[w] = (int)(~(unsigned)b);
      __syncthreads();
    }
    if (tid < 64) {
      const int r = tid >> 3, c = tid & 7;
      ((float4*)sX[r])[c] = ((const float4*)(p.demb + (size_t)sTok[r] * 32))[c];
    }
    __syncthreads();

    // ---- LSTM layer 0 (thread = gate g for 2 rows) ----
    {
      const int g = tid & 127, rp = tid >> 7;
      float4 wi[8], wh[8];
#pragma unroll
      for (int jo = 0; jo < 8; ++jo) { wi[jo] = cw4[jo * 128 + g]; wh[jo] = cw4[1024 + jo * 128 + g]; }
      const float bb = sB[0][g];
#pragma unroll
      for (int rr = 0; rr < 2; ++rr) {
        const int r = rp * 2 + rr;
        const float4* x4 = (const float4*)sX[r];
        const float4* h4 = (const float4*)sH0[r];
        float a = bb;
#pragma unroll
        for (int jo = 0; jo < 8; ++jo) a += dot4(wi[jo], x4[jo]) + dot4(wh[jo], h4[jo]);
        sG[r][g] = a;
      }
    }
    __syncthreads();
    if (tid < 256) {
      const int r = tid >> 5, j = tid & 31;
      const float gi = sigm(sG[r][j]), gf = sigm(sG[r][32 + j]);
      const float gg = tanhf(sG[r][64 + j]), go = sigm(sG[r][96 + j]);
      const float c = gf * sC0[r][j] + gi * gg;
      sC0[r][j] = c; sH0[r][j] = go * tanhf(c);
    }
    __syncthreads();

    // ---- LSTM layer 1 ----
    {
      const int g = tid & 127, rp = tid >> 7;
      float4 wi[8], wh[8];
#pragma unroll
      for (int jo = 0; jo < 8; ++jo) { wi[jo] = cw4[2048 + jo * 128 + g]; wh[jo] = cw4[3072 + jo * 128 + g]; }
      const float bb = sB[1][g];
#pragma unroll
      for (int rr = 0; rr < 2; ++rr) {
        const int r = rp * 2 + rr;
        const float4* x4 = (const float4*)sH0[r];
        const float4* h4 = (const float4*)sH1[r];
        float a = bb;
#pragma unroll
        for (int jo = 0; jo < 8; ++jo) a += dot4(wi[jo], x4[jo]) + dot4(wh[jo], h4[jo]);
        sG[r][g] = a;
      }
    }
    __syncthreads();
    if (tid < 256) {
      const int r = tid >> 5, j = tid & 31;
      const float gi = sigm(sG[r][j]), gf = sigm(sG[r][32 + j]);
      const float gg = tanhf(sG[r][64 + j]), go = sigm(sG[r][96 + j]);
      const float c = gf * sC1[r][j] + gi * gg;
      sC1[r][j] = c; sH1[r][j] = go * tanhf(c);
    }
    __syncthreads();

    // ---- logits + argmax: halves of 256 threads -> 4 rows each ----
    {
      const int half = tid >> 8, lane256 = tid & 255;
      float4 hr[4][8];                 // 128 VGPRs; fits under the 256-VGPR cap
#pragma unroll
      for (int k = 0; k < 4; ++k) {
        const float4* h4 = (const float4*)sH1[half * 4 + k];
#pragma unroll
        for (int c = 0; c < 8; ++c) hr[k][c] = h4[c];
      }
      unsigned long long best[4] = {0ull, 0ull, 0ull, 0ull};
      const size_t ob = ((size_t)t * 32 + R + half * 4) * VOCAB;
      for (int v = v0 + lane256; v < v1; v += 256) {
        float4 w0, w1, w2, w3, w4, w5, w6, w7;
        if (p.use_pack) {
          w0 = p.fcp[v];              w1 = p.fcp[VPAD + v];
          w2 = p.fcp[2 * VPAD + v];   w3 = p.fcp[3 * VPAD + v];
          w4 = p.fcp[4 * VPAD + v];   w5 = p.fcp[5 * VPAD + v];
          w6 = p.fcp[6 * VPAD + v];   w7 = p.fcp[7 * VPAD + v];
        } else {
          const float4* wp = (const float4*)(p.fcW + (size_t)v * 32);
          w0 = wp[0]; w1 = wp[1]; w2 = wp[2]; w3 = wp[3];
          w4 = wp[4]; w5 = wp[5]; w6 = wp[6]; w7 = wp[7];
        }
        const float bb = p.fcb[v];
#pragma unroll
        for (int k = 0; k < 4; ++k) {
          float a = bb
            + dot4(hr[k][0], w0) + dot4(hr[k][1], w1) + dot4(hr[k][2], w2) + dot4(hr[k][3], w3)
            + dot4(hr[k][4], w4) + dot4(hr[k][5], w5) + dot4(hr[k][6], w6) + dot4(hr[k][7], w7);
          __builtin_nontemporal_store(a, &p.out[ob + (size_t)k * VOCAB + v]);  // don't evict fcp from L2
          unsigned ui = __float_as_uint(a);
          ui = (ui & 0x80000000u) ? ~ui : (ui | 0x80000000u);   // monotone float->uint
          const unsigned long long pk = ((unsigned long long)ui << 32) | (unsigned)(~(unsigned)v);
          if (pk > best[k]) best[k] = pk;   // ties -> smallest v (matches jnp.argmax)
        }
      }
#pragma unroll
      for (int off = 32; off > 0; off >>= 1)
#pragma unroll
        for (int k = 0; k < 4; ++k) {
          const unsigned long long o = __shfl_down(best[k], (unsigned)off, 64);
          if (o > best[k]) best[k] = o;
        }
      if ((tid & 63) == 0) {
        const int w = tid >> 6;
#pragma unroll
        for (int k = 0; k < 4; ++k) redw[w][k] = best[k];
      }
    }
    __syncthreads();
    if (t != SDEC - 1) {
      if (tid < 8) {   // row R+tid: combine the 4 wave-candidates, publish slice-best
        const int wb = (tid >> 2) * 4, k = tid & 3;
        unsigned long long m = redw[wb][k];
        if (redw[wb + 1][k] > m) m = redw[wb + 1][k];
        if (redw[wb + 2][k] > m) m = redw[wb + 2][k];
        if (redw[wb + 3][k] > m) m = redw[wb + 3][k];
        __hip_atomic_store(&p.cand[(((size_t)(t & 1) * 8 + rg) * 8 + tid) * 64 + slice], m,
                           __ATOMIC_RELAXED, __HIP_MEMORY_SCOPE_AGENT);
      }
      if (tid == 0)   // same wave as the cand stores; RELEASE drains them first
        __hip_atomic_store(&p.dflag[rg * 64 + slice], (unsigned)(t + 1),
                           __ATOMIC_RELEASE, __HIP_MEMORY_SCOPE_AGENT);
    }
  }
}

extern "C" void kernel_launch(void* const* d_in, const int* in_sizes, int n_in,
                              void* d_out, int out_size, void* d_ws, size_t ws_size,
                              hipStream_t stream) {
  Params p;
  p.xsrc  = (const int*)d_in[0];
  p.xtgt  = (const int*)d_in[1];
  p.eemb  = (const float*)d_in[2];
  p.eWih0 = (const float*)d_in[3];
  p.eWhh0 = (const float*)d_in[4];
  p.ebih0 = (const float*)d_in[5];
  p.ebhh0 = (const float*)d_in[6];
  p.eWih1 = (const float*)d_in[7];
  p.eWhh1 = (const float*)d_in[8];
  p.ebih1 = (const float*)d_in[9];
  p.ebhh1 = (const float*)d_in[10];
  p.demb  = (const float*)d_in[11];
  p.dWih0 = (const float*)d_in[12];
  p.dWhh0 = (const float*)d_in[13];
  p.dbih0 = (const float*)d_in[14];
  p.dbhh0 = (const float*)d_in[15];
  p.dWih1 = (const float*)d_in[16];
  p.dWhh1 = (const float*)d_in[17];
  p.dbih1 = (const float*)d_in[18];
  p.dbhh1 = (const float*)d_in[19];
  p.fcW   = (const float*)d_in[20];
  p.fcb   = (const float*)d_in[21];
  p.out   = (float*)d_out;

  char* ws = (char*)d_ws;
  p.sflag = (unsigned*)(ws);                   // 128 B (pad to 1 KB)
  p.dflag = (unsigned*)(ws + 1024);            // 2 KB
  p.Sh0   = (float*)(ws + 4096);               // 4 KB each
  p.Sc0   = (float*)(ws + 8192);
  p.Sh1   = (float*)(ws + 12288);
  p.Sc1   = (float*)(ws + 16384);
  p.cand  = (unsigned long long*)(ws + 20480); // 2*8*8*64*8 = 64 KB
  p.fcp   = (float4*)(ws + 98304);             // 8*VPAD*16 = 6438912 B
  const size_t need = 98304 + (size_t)8 * VPAD * 16;
  p.use_pack = (ws_size >= need) ? 1 : 0;      // fallback: row-major direct reads

  init_kernel<<<dim3(64), dim3(256), 0, stream>>>(p);
  fused_kernel<<<dim3(NBLK), dim3(NTHR), 0, stream>>>(p);
}

// Round 3
// 1281.655 us; speedup vs baseline: 1.7261x; 1.6651x over previous
//
#include <hip/hip_runtime.h>

#define VOCAB  50257
#define VPAD   50304          // 64*786 padded vocab
#define SLICE  786            // vocab per slice (64 slices)
#define SDEC   63             // decode steps (S_TGT-1)
#define NBLK   256            // 1 block/CU, all resident by resource arithmetic
#define NTHR   512            // 8 waves/block

struct Params {
  const int   *xsrc, *xtgt;
  const float *eemb, *eWih0, *eWhh0, *ebih0, *ebhh0, *eWih1, *eWhh1, *ebih1, *ebhh1;
  const float *demb, *dWih0, *dWhh0, *dbih0, *dbhh0, *dWih1, *dWhh1, *dbih1, *dbhh1;
  const float *fcW, *fcb;
  float *out;
  unsigned *sflag;              // [32] encoder-row done flags
  unsigned long long *cand;     // [2][4][8][64] tagged argmax candidates (flag==data)
  float *Sh0, *Sc0, *Sh1, *Sc1; // [32*32] encoder-final states
  float4 *fcp;                  // [8*VPAD] transposed fc_W
  int use_pack;
};

__device__ __forceinline__ float sigm(float x) { return 1.f / (1.f + expf(-x)); }
__device__ __forceinline__ float dot4(float4 a, float4 b) {
  return a.x * b.x + a.y * b.y + a.z * b.z + a.w * b.w;
}

// ---------------- init: flag/cand reset + fc_W transpose pack ----------------
__global__ __launch_bounds__(256) void init_kernel(Params p)
{
  const int tid = threadIdx.x, blk = blockIdx.x;
  if (blk == 0) {
    if (tid < 32) p.sflag[tid] = 0u;                 // MUST reset every graph replay
    for (int i = tid; i < 2 * 4 * 8 * 64; i += 256) p.cand[i] = 0ull;  // tag 0
  }
  if (p.use_pack) {
    const int gid = blk * 256 + tid, stride = 64 * 256;
    for (int v = gid; v < VOCAB; v += stride) {
      const float4* s = (const float4*)(p.fcW + (size_t)v * 32);
#pragma unroll
      for (int c = 0; c < 8; ++c) p.fcp[(size_t)c * VPAD + v] = s[c];
    }
  }
}

// ---------------- fused encoder + full greedy decode, tag-in-payload sync ----------------
// block b: vocab slice = b & 63, row-group rg = b >> 6 (4 groups x 8 rows).
// candidate u64 = [tag:8][monotone-ui:32][~v:16][0:8]; tag==step+1. The payload IS the
// flag: no release/acquire ordering needed, one L3 hop per step instead of two+drain.
__global__ __launch_bounds__(NTHR, 1) void fused_kernel(Params p)
{
  const int tid = threadIdx.x, blk = blockIdx.x;
  const int slice = blk & 63, rg = blk >> 6;
  const int R = rg * 8;
  const int v0 = slice * SLICE, v1 = min(VOCAB, v0 + SLICE);

  __shared__ __align__(16) float4 cw4[4096];       // 64KB decoder cell weights (transposed)
  __shared__ __align__(16) float4 fcpL[8][512];    // 64KB: fc slice, iters 0-1 (step-invariant)
  __shared__ float sFcb[1024];                     // fc bias for the whole slice
  __shared__ float sB[2][128];
  __shared__ __align__(16) float sH0[8][32], sC0[8][32], sH1[8][32], sC1[8][32], sX[8][32];
  __shared__ __align__(16) float sG[8][128];
  __shared__ int sTok[8];
  __shared__ unsigned long long redw[8][4];
  __shared__ __align__(16) float eH0[32], eC0[32], eH1[32], eC1[32];
  __shared__ float eG[128];

  // decoder cell weights -> LDS (transposed, conflict-free b128 reads later)
  for (int i = tid; i < 4096; i += NTHR) {
    const int mat = i >> 10, rem = i & 1023, jo = rem >> 7, g = rem & 127;
    const float* W = (mat == 0) ? p.dWih0 : (mat == 1) ? p.dWhh0
                   : (mat == 2) ? p.dWih1 : p.dWhh1;
    const float* s = W + g * 32 + jo * 4;
    cw4[i] = make_float4(s[0], s[1], s[2], s[3]);
  }
  // fc slice iters 0-1 -> LDS (v0+0 .. v0+511; always < VOCAB since v0 <= 49518)
  for (int idx = tid; idx < 4096; idx += NTHR) {
    const int c = idx >> 9, i = idx & 511;
    if (p.use_pack) fcpL[c][i] = p.fcp[(size_t)c * VPAD + v0 + i];
    else            fcpL[c][i] = ((const float4*)(p.fcW + (size_t)(v0 + i) * 32))[c];
  }
  for (int i = tid; i < 1024; i += NTHR)
    sFcb[i] = (i < SLICE && v0 + i < VOCAB) ? p.fcb[v0 + i] : 0.f;
  if (tid < 128) {
    sB[0][tid] = p.dbih0[tid] + p.dbhh0[tid];
    sB[1][tid] = p.dbih1[tid] + p.dbhh1[tid];
  }

  // ---- phase A: blocks 0..31 run the encoder for batch row `blk` ----
  if (blk < 32) {
    float4 wi0[8], wh0[8], wi1[8], wh1[8];
    float bs0 = 0.f, bs1 = 0.f;
    if (tid < 128) {
      const float4* a0 = (const float4*)(p.eWih0 + tid * 32);
      const float4* b0 = (const float4*)(p.eWhh0 + tid * 32);
      const float4* a1 = (const float4*)(p.eWih1 + tid * 32);
      const float4* b1 = (const float4*)(p.eWhh1 + tid * 32);
#pragma unroll
      for (int c = 0; c < 8; ++c) { wi0[c] = a0[c]; wh0[c] = b0[c]; wi1[c] = a1[c]; wh1[c] = b1[c]; }
      bs0 = p.ebih0[tid] + p.ebhh0[tid];
      bs1 = p.ebih1[tid] + p.ebhh1[tid];
    }
    if (tid < 32) { eH0[tid] = 0.f; eC0[tid] = 0.f; eH1[tid] = 0.f; eC1[tid] = 0.f; }
    __syncthreads();
    for (int t = 0; t < 64; ++t) {
      const int tok = p.xsrc[t * 32 + blk];
      if (tid < 128) {
        const float4* xe = (const float4*)(p.eemb + (size_t)tok * 32);
        const float4* h4 = (const float4*)eH0;
        float a = bs0;
#pragma unroll
        for (int c = 0; c < 8; ++c) a += dot4(wi0[c], xe[c]) + dot4(wh0[c], h4[c]);
        eG[tid] = a;
      }
      __syncthreads();
      if (tid < 32) {
        float gi = sigm(eG[tid]), gf = sigm(eG[32 + tid]);
        float gg = tanhf(eG[64 + tid]), go = sigm(eG[96 + tid]);
        float c = gf * eC0[tid] + gi * gg;
        eC0[tid] = c; eH0[tid] = go * tanhf(c);
      }
      __syncthreads();
      if (tid < 128) {
        const float4* x4 = (const float4*)eH0;
        const float4* h4 = (const float4*)eH1;
        float a = bs1;
#pragma unroll
        for (int c = 0; c < 8; ++c) a += dot4(wi1[c], x4[c]) + dot4(wh1[c], h4[c]);
        eG[tid] = a;
      }
      __syncthreads();
      if (tid < 32) {
        float gi = sigm(eG[tid]), gf = sigm(eG[32 + tid]);
        float gg = tanhf(eG[64 + tid]), go = sigm(eG[96 + tid]);
        float c = gf * eC1[tid] + gi * gg;
        eC1[tid] = c; eH1[tid] = go * tanhf(c);
      }
      __syncthreads();
    }
    if (tid < 32) {
      __hip_atomic_store(&p.Sh0[blk * 32 + tid], eH0[tid], __ATOMIC_RELAXED, __HIP_MEMORY_SCOPE_AGENT);
      __hip_atomic_store(&p.Sc0[blk * 32 + tid], eC0[tid], __ATOMIC_RELAXED, __HIP_MEMORY_SCOPE_AGENT);
      __hip_atomic_store(&p.Sh1[blk * 32 + tid], eH1[tid], __ATOMIC_RELAXED, __HIP_MEMORY_SCOPE_AGENT);
      __hip_atomic_store(&p.Sc1[blk * 32 + tid], eC1[tid], __ATOMIC_RELAXED, __HIP_MEMORY_SCOPE_AGENT);
    }
    if (tid == 0)   // RELEASE drains the state stores before the flag lands
      __hip_atomic_store(&p.sflag[blk], 1u, __ATOMIC_RELEASE, __HIP_MEMORY_SCOPE_AGENT);
  }

  // ---- wait only for THIS block's 8 rows of encoder state ----
  if (tid < 8) {
    while (__hip_atomic_load(&p.sflag[R + tid], __ATOMIC_RELAXED, __HIP_MEMORY_SCOPE_AGENT) == 0u)
      __builtin_amdgcn_s_sleep(1);
    (void)__hip_atomic_load(&p.sflag[R + tid], __ATOMIC_ACQUIRE, __HIP_MEMORY_SCOPE_AGENT);
  }
  __syncthreads();
  if (tid < 256) {
    const int r = tid >> 5, j = tid & 31, gi = (R + r) * 32 + j;
    sH0[r][j] = __hip_atomic_load(&p.Sh0[gi], __ATOMIC_RELAXED, __HIP_MEMORY_SCOPE_AGENT);
    sC0[r][j] = __hip_atomic_load(&p.Sc0[gi], __ATOMIC_RELAXED, __HIP_MEMORY_SCOPE_AGENT);
    sH1[r][j] = __hip_atomic_load(&p.Sh1[gi], __ATOMIC_RELAXED, __HIP_MEMORY_SCOPE_AGENT);
    sC1[r][j] = __hip_atomic_load(&p.Sc1[gi], __ATOMIC_RELAXED, __HIP_MEMORY_SCOPE_AGENT);
  }
  __syncthreads();

  for (int t = 0; t < SDEC; ++t) {
    // ---- tokens: xtgt at t=0, else poll+reduce the 64 tagged slice-candidates ----
    if (t == 0) {
      if (tid < 8) sTok[tid] = p.xtgt[R + tid];
    } else {
      const int w = tid >> 6, ln = tid & 63;     // wave w reduces row R+w, lane = slice
      const size_t ci = ((((size_t)((t - 1) & 1)) * 4 + rg) * 8 + w) * 64 + ln;
      unsigned long long x = __hip_atomic_load(&p.cand[ci], __ATOMIC_RELAXED, __HIP_MEMORY_SCOPE_AGENT);
      while ((unsigned)(x >> 56) != (unsigned)t) {
        __builtin_amdgcn_s_sleep(1);
        x = __hip_atomic_load(&p.cand[ci], __ATOMIC_RELAXED, __HIP_MEMORY_SCOPE_AGENT);
      }
#pragma unroll
      for (int off = 32; off > 0; off >>= 1) {
        const unsigned long long o = __shfl_down(x, (unsigned)off, 64);
        if (o > x) x = o;
      }
      if (ln == 0) sTok[w] = 0xFFFF - (int)((x >> 8) & 0xFFFF);   // v = 65535 - nv16
    }
    __syncthreads();
    if (tid < 64) {
      const int r = tid >> 3, c = tid & 7;
      ((float4*)sX[r])[c] = ((const float4*)(p.demb + (size_t)sTok[r] * 32))[c];
    }
    __syncthreads();

    // ---- LSTM layer 0 (thread = gate g for 2 rows) ----
    {
      const int g = tid & 127, rp = tid >> 7;
      float4 wi[8], wh[8];
#pragma unroll
      for (int jo = 0; jo < 8; ++jo) { wi[jo] = cw4[jo * 128 + g]; wh[jo] = cw4[1024 + jo * 128 + g]; }
      const float bb = sB[0][g];
#pragma unroll
      for (int rr = 0; rr < 2; ++rr) {
        const int r = rp * 2 + rr;
        const float4* x4 = (const float4*)sX[r];
        const float4* h4 = (const float4*)sH0[r];
        float a = bb;
#pragma unroll
        for (int jo = 0; jo < 8; ++jo) a += dot4(wi[jo], x4[jo]) + dot4(wh[jo], h4[jo]);
        sG[r][g] = a;
      }
    }
    __syncthreads();
    if (tid < 256) {
      const int r = tid >> 5, j = tid & 31;
      const float gi = sigm(sG[r][j]), gf = sigm(sG[r][32 + j]);
      const float gg = tanhf(sG[r][64 + j]), go = sigm(sG[r][96 + j]);
      const float c = gf * sC0[r][j] + gi * gg;
      sC0[r][j] = c; sH0[r][j] = go * tanhf(c);
    }
    __syncthreads();

    // ---- LSTM layer 1 ----
    {
      const int g = tid & 127, rp = tid >> 7;
      float4 wi[8], wh[8];
#pragma unroll
      for (int jo = 0; jo < 8; ++jo) { wi[jo] = cw4[2048 + jo * 128 + g]; wh[jo] = cw4[3072 + jo * 128 + g]; }
      const float bb = sB[1][g];
#pragma unroll
      for (int rr = 0; rr < 2; ++rr) {
        const int r = rp * 2 + rr;
        const float4* x4 = (const float4*)sH0[r];
        const float4* h4 = (const float4*)sH1[r];
        float a = bb;
#pragma unroll
        for (int jo = 0; jo < 8; ++jo) a += dot4(wi[jo], x4[jo]) + dot4(wh[jo], h4[jo]);
        sG[r][g] = a;
      }
    }
    __syncthreads();
    if (tid < 256) {
      const int r = tid >> 5, j = tid & 31;
      const float gi = sigm(sG[r][j]), gf = sigm(sG[r][32 + j]);
      const float gg = tanhf(sG[r][64 + j]), go = sigm(sG[r][96 + j]);
      const float c = gf * sC1[r][j] + gi * gg;
      sC1[r][j] = c; sH1[r][j] = go * tanhf(c);
    }
    __syncthreads();

    // ---- logits + argmax; out-stores DEFERRED until after candidate publish ----
    const int half = tid >> 8, lane256 = tid & 255;
    const size_t ob = ((size_t)t * 32 + R + half * 4) * VOCAB;
    float vals[4][4];
    {
      float4 hr[4][8];
#pragma unroll
      for (int k = 0; k < 4; ++k) {
        const float4* h4 = (const float4*)sH1[half * 4 + k];
#pragma unroll
        for (int c = 0; c < 8; ++c) hr[k][c] = h4[c];
      }
      unsigned long long best[4] = {0ull, 0ull, 0ull, 0ull};
#pragma unroll
      for (int it = 0; it < 4; ++it) {
        const int v = v0 + lane256 + (it << 8);
        if (v < v1) {
          float4 w0, w1, w2, w3, w4, w5, w6, w7;
          if (it < 2) {                       // L2-latency-free: step-invariant LDS copy
            const int li = lane256 + (it << 8);
            w0 = fcpL[0][li]; w1 = fcpL[1][li]; w2 = fcpL[2][li]; w3 = fcpL[3][li];
            w4 = fcpL[4][li]; w5 = fcpL[5][li]; w6 = fcpL[6][li]; w7 = fcpL[7][li];
          } else if (p.use_pack) {
            w0 = p.fcp[v];              w1 = p.fcp[VPAD + v];
            w2 = p.fcp[2 * VPAD + v];   w3 = p.fcp[3 * VPAD + v];
            w4 = p.fcp[4 * VPAD + v];   w5 = p.fcp[5 * VPAD + v];
            w6 = p.fcp[6 * VPAD + v];   w7 = p.fcp[7 * VPAD + v];
          } else {
            const float4* wp = (const float4*)(p.fcW + (size_t)v * 32);
            w0 = wp[0]; w1 = wp[1]; w2 = wp[2]; w3 = wp[3];
            w4 = wp[4]; w5 = wp[5]; w6 = wp[6]; w7 = wp[7];
          }
          const float bb = sFcb[v - v0];
#pragma unroll
          for (int k = 0; k < 4; ++k) {
            float a = bb
              + dot4(hr[k][0], w0) + dot4(hr[k][1], w1) + dot4(hr[k][2], w2) + dot4(hr[k][3], w3)
              + dot4(hr[k][4], w4) + dot4(hr[k][5], w5) + dot4(hr[k][6], w6) + dot4(hr[k][7], w7);
            vals[it][k] = a;
            unsigned ui = __float_as_uint(a);
            ui = (ui & 0x80000000u) ? ~ui : (ui | 0x80000000u);   // monotone float->uint
            // [ui:32 @24][~v:16 @8]; ties -> smallest v (matches jnp.argmax)
            const unsigned long long pk =
              ((unsigned long long)ui << 24) | ((unsigned long long)(0xFFFFu - (unsigned)v) << 8);
            if (pk > best[k]) best[k] = pk;
          }
        }
      }
#pragma unroll
      for (int off = 32; off > 0; off >>= 1)
#pragma unroll
        for (int k = 0; k < 4; ++k) {
          const unsigned long long o = __shfl_down(best[k], (unsigned)off, 64);
          if (o > best[k]) best[k] = o;
        }
      if ((tid & 63) == 0) {
        const int w = tid >> 6;
#pragma unroll
        for (int k = 0; k < 4; ++k) redw[w][k] = best[k];
      }
    }
    __syncthreads();
    if (t != SDEC - 1) {
      if (tid < 8) {   // row R+tid: combine 4 wave-candidates, publish tagged payload
        const int wb = (tid >> 2) * 4, k = tid & 3;
        unsigned long long m = redw[wb][k];
        if (redw[wb + 1][k] > m) m = redw[wb + 1][k];
        if (redw[wb + 2][k] > m) m = redw[wb + 2][k];
        if (redw[wb + 3][k] > m) m = redw[wb + 3][k];
        m |= ((unsigned long long)(unsigned)(t + 1) << 56);      // tag = step+1
        const size_t ci = ((((size_t)(t & 1)) * 4 + rg) * 8 + tid) * 64 + slice;
        __hip_atomic_store(&p.cand[ci], m, __ATOMIC_RELAXED, __HIP_MEMORY_SCOPE_AGENT);
      }
    }
    // deferred out-stores: overlap the next step's poll instead of gating the publish
#pragma unroll
    for (int it = 0; it < 4; ++it) {
      const int v = v0 + lane256 + (it << 8);
      if (v < v1) {
#pragma unroll
        for (int k = 0; k < 4; ++k)
          __builtin_nontemporal_store(vals[it][k], &p.out[ob + (size_t)k * VOCAB + v]);
      }
    }
  }
}

extern "C" void kernel_launch(void* const* d_in, const int* in_sizes, int n_in,
                              void* d_out, int out_size, void* d_ws, size_t ws_size,
                              hipStream_t stream) {
  Params p;
  p.xsrc  = (const int*)d_in[0];
  p.xtgt  = (const int*)d_in[1];
  p.eemb  = (const float*)d_in[2];
  p.eWih0 = (const float*)d_in[3];
  p.eWhh0 = (const float*)d_in[4];
  p.ebih0 = (const float*)d_in[5];
  p.ebhh0 = (const float*)d_in[6];
  p.eWih1 = (const float*)d_in[7];
  p.eWhh1 = (const float*)d_in[8];
  p.ebih1 = (const float*)d_in[9];
  p.ebhh1 = (const float*)d_in[10];
  p.demb  = (const float*)d_in[11];
  p.dWih0 = (const float*)d_in[12];
  p.dWhh0 = (const float*)d_in[13];
  p.dbih0 = (const float*)d_in[14];
  p.dbhh0 = (const float*)d_in[15];
  p.dWih1 = (const float*)d_in[16];
  p.dWhh1 = (const float*)d_in[17];
  p.dbih1 = (const float*)d_in[18];
  p.dbhh1 = (const float*)d_in[19];
  p.fcW   = (const float*)d_in[20];
  p.fcb   = (const float*)d_in[21];
  p.out   = (float*)d_out;

  char* ws = (char*)d_ws;
  p.sflag = (unsigned*)(ws);                   // 128 B
  p.Sh0   = (float*)(ws + 1024);               // 4 KB each
  p.Sc0   = (float*)(ws + 5120);
  p.Sh1   = (float*)(ws + 9216);
  p.Sc1   = (float*)(ws + 13312);
  p.cand  = (unsigned long long*)(ws + 20480); // 2*4*8*64*8 = 32 KB
  p.fcp   = (float4*)(ws + 65536);             // 8*VPAD*16 = 6438912 B
  const size_t need = 65536 + (size_t)8 * VPAD * 16;
  p.use_pack = (ws_size >= need) ? 1 : 0;      // fallback: row-major direct reads

  init_kernel<<<dim3(64), dim3(256), 0, stream>>>(p);
  fused_kernel<<<dim3(NBLK), dim3(NTHR), 0, stream>>>(p);
}